// Round 6
// baseline (75.246 us; speedup 1.0000x reference)
//
#include <hip/hip_runtime.h>
#include <math.h>

// PhaseLoss: ip + gd + ptd phase losses over [32,1,513,512] fp32 spectra.
// d'[b,f,t] = angle(ref * conj(est)); ip = |d'|;
// gd  = unwrap(d'[f-1,t] - d'[f,t])  (f-1<0 -> 0)
// ptd = unwrap(d'[f,t-1] - d'[f,t])  (t-1<0 -> 0)
// out = sum / (B*F*T)
//
// Structure: register-carried f-loop, RPW=4 rows/wave (+1 recomputed halo
// row), explicit ping-pong double buffer (named A/B, fully unrolled -> both
// buffers live in VGPRs; loads for row r+1 stay in flight across row r's
// compute; R5 lesson: VGPR_Count=44 meant the prefetch was being demoted).
// No LDS staging, no threadfence (R4 lesson: device-scope fence = L2
// writeback+invalidate per block on gfx950). No finalize kernel: per-wave
// reduce -> one fp32 atomicAdd of s/N to out[0]; out zeroed via memsetAsync.

#define NB 32
#define NF 513
#define NT 512
#define RPW 4
#define CHUNKS 129         // ceil(513/4)
#define NBLOCKS 1032       // 32*129 waves / 4 waves per block
#define NTOT 8404992LL     // 32*513*512
#define INV_NTOT 1.189769845796482e-7f

static __device__ __forceinline__ float fast_atan2(float y, float x) {
    const float PI_F  = 3.14159274101257324f;
    const float PI_2F = 1.57079632679489662f;
    float ax = fabsf(x), ay = fabsf(y);
    float mx = fmaxf(ax, ay), mn = fminf(ax, ay);
    float r  = mn * __builtin_amdgcn_rcpf(mx);
    r = (mx == 0.f) ? 0.f : r;
    float s = r * r;
    float p = fmaf(s, -0.01172120f, 0.05265332f);
    p = fmaf(s, p, -0.11643287f);
    p = fmaf(s, p,  0.19354346f);
    p = fmaf(s, p, -0.33262347f);
    p = fmaf(s, p,  0.99997726f);
    float a = r * p;
    a = (ay > ax) ? (PI_2F - a) : a;
    a = (x < 0.f) ? (PI_F - a) : a;
    return copysignf(a, y);
}

static __device__ __forceinline__ float pdiff(float a, float b, float c, float d) {
    // est=a+ib, ref=c+id: angle(ref*conj(est)) = atan2(d*a - c*b, c*a + d*b)
    return fast_atan2(fmaf(d, a, -(c * b)), fmaf(c, a, d * b));
}

static __device__ __forceinline__ float wrap_abs(float x) {
    const float PI_F     = 3.14159274101257324f;
    const float TWO_PI_F = 6.28318548202514648f;
    float u = fabsf(x);
    return u > PI_F ? TWO_PI_F - u : u;
}

struct Row8 { float4 a0, a1, b0, b1, c0, c1, e0, e1; };

static __device__ __forceinline__ void calc8(const Row8& r, float d[8]) {
    d[0] = pdiff(r.a0.x, r.b0.x, r.c0.x, r.e0.x);
    d[1] = pdiff(r.a0.y, r.b0.y, r.c0.y, r.e0.y);
    d[2] = pdiff(r.a0.z, r.b0.z, r.c0.z, r.e0.z);
    d[3] = pdiff(r.a0.w, r.b0.w, r.c0.w, r.e0.w);
    d[4] = pdiff(r.a1.x, r.b1.x, r.c1.x, r.e1.x);
    d[5] = pdiff(r.a1.y, r.b1.y, r.c1.y, r.e1.y);
    d[6] = pdiff(r.a1.z, r.b1.z, r.c1.z, r.e1.z);
    d[7] = pdiff(r.a1.w, r.b1.w, r.c1.w, r.e1.w);
}

__global__ __launch_bounds__(256) void phase_loss_k(
    const float* __restrict__ er, const float* __restrict__ ei,
    const float* __restrict__ rr, const float* __restrict__ ri,
    float* __restrict__ out)
{
    const int tid  = threadIdx.x;
    const int lane = tid & 63;
    const int wid  = (blockIdx.x << 2) | (tid >> 6);   // 0..4127
    const int b    = wid / CHUNKS;
    const int f0   = (wid - b * CHUNKS) * RPW;
    const int base = b * (NF * NT);
    const int nv   = (NF - f0 < RPW) ? (NF - f0) : RPW;   // 4, or 1 on last chunk

#define LOAD_ROW(dst, f_) do {                                   \
        const int _i = base + (f_) * NT + lane * 8;              \
        dst.a0 = *(const float4*)(er + _i);                      \
        dst.a1 = *(const float4*)(er + _i + 4);                  \
        dst.b0 = *(const float4*)(ei + _i);                      \
        dst.b1 = *(const float4*)(ei + _i + 4);                  \
        dst.c0 = *(const float4*)(rr + _i);                      \
        dst.c1 = *(const float4*)(rr + _i + 4);                  \
        dst.e0 = *(const float4*)(ri + _i);                      \
        dst.e1 = *(const float4*)(ri + _i + 4);                  \
    } while (0)

    float s = 0.f;
    float dp[8], d[8];
    Row8 A, B;

    // accumulate one row: ip + gd(f-1 from dp) + ptd(t-1 via shfl); dp <- d
#define ACC_ROW() do {                                           \
        float dt = __shfl_up(d[7], 1, 64);                       \
        if (lane == 0) dt = 0.f;                                 \
        _Pragma("unroll")                                        \
        for (int k = 0; k < 8; ++k) {                            \
            s += fabsf(d[k]);                                    \
            s += wrap_abs(dp[k] - d[k]);                         \
            s += wrap_abs(dt - d[k]);                            \
            dt = d[k];                                           \
            dp[k] = d[k];                                        \
        }                                                        \
    } while (0)

    // ---- software pipeline, ping-pong A/B, fully unrolled ----
    if (f0 > 0) LOAD_ROW(A, f0 - 1);          // halo row
    LOAD_ROW(B, f0);                           // row 0 in flight
    if (f0 > 0) {
        calc8(A, dp);                          // waits only A's loads
    } else {
        #pragma unroll
        for (int k = 0; k < 8; ++k) dp[k] = 0.f;
    }
    if (nv > 1) LOAD_ROW(A, f0 + 1);          // issue before consuming B
    calc8(B, d);  ACC_ROW();                   // row 0
    if (nv > 1) {
        if (nv > 2) LOAD_ROW(B, f0 + 2);
        calc8(A, d);  ACC_ROW();               // row 1
        if (nv > 2) {
            if (nv > 3) LOAD_ROW(A, f0 + 3);
            calc8(B, d);  ACC_ROW();           // row 2
            if (nv > 3) {
                calc8(A, d);  ACC_ROW();       // row 3
            }
        }
    }
#undef LOAD_ROW
#undef ACC_ROW

    // per-wave reduce; one scaled fp32 atomic per wave (no finalize kernel)
    #pragma unroll
    for (int off = 32; off > 0; off >>= 1)
        s += __shfl_down(s, off, 64);
    if (lane == 0) atomicAdd(out, s * INV_NTOT);
}

extern "C" void kernel_launch(void* const* d_in, const int* in_sizes, int n_in,
                              void* d_out, int out_size, void* d_ws, size_t ws_size,
                              hipStream_t stream) {
    const float* er = (const float*)d_in[0];
    const float* ei = (const float*)d_in[1];
    const float* rr = (const float*)d_in[2];
    const float* ri = (const float*)d_in[3];
    float* out = (float*)d_out;

    hipMemsetAsync(out, 0, sizeof(float), stream);   // out accumulates atomically
    phase_loss_k<<<NBLOCKS, 256, 0, stream>>>(er, ei, rr, ri, out);
}

// Round 7
// 35.847 us; speedup vs baseline: 2.0991x; 2.0991x over previous
//
#include <hip/hip_runtime.h>
#include <math.h>

// PhaseLoss: ip + gd + ptd phase losses over [32,1,513,512] fp32 spectra.
// d'[b,f,t] = angle(ref * conj(est)); ip = |d'|;
// gd  = unwrap(d'[f-1,t] - d'[f,t])  (f-1<0 -> 0)
// ptd = unwrap(d'[f,t-1] - d'[f,t])  (t-1<0 -> 0)
// out = sum / (B*F*T)
//
// Structure: TWO independent row-streams per wave (RPW=4 rows + 1 recomputed
// halo row each). Interleaved schedule calc(A)/load(B)/calc(B)/load(A): one
// stream's 8KB of loads stays in flight during the other stream's atan2 work
// (counted vmcnt, compiler-friendly because the streams share no dataflow).
// R6 lessons applied: no single-address atomics, no fused tail, no fences.
// Slots are plain per-block stores; tiny finalize kernel sums them.

#define NB 32
#define NF 513
#define NT 512
#define RPW 4
#define CHUNKS 129         // ceil(513/4) chunks per batch
#define NSTREAMS 4128      // 32*129
#define NWAVES 2064        // 2 streams per wave
#define NBLOCKS 516        // 4 waves per block
#define NTOT 8404992LL     // 32*513*512

static __device__ __forceinline__ float fast_atan2(float y, float x) {
    const float PI_F  = 3.14159274101257324f;
    const float PI_2F = 1.57079632679489662f;
    float ax = fabsf(x), ay = fabsf(y);
    float mx = fmaxf(ax, ay), mn = fminf(ax, ay);
    float r  = mn * __builtin_amdgcn_rcpf(mx);
    r = (mx == 0.f) ? 0.f : r;
    float s = r * r;
    float p = fmaf(s, -0.01172120f, 0.05265332f);
    p = fmaf(s, p, -0.11643287f);
    p = fmaf(s, p,  0.19354346f);
    p = fmaf(s, p, -0.33262347f);
    p = fmaf(s, p,  0.99997726f);
    float a = r * p;
    a = (ay > ax) ? (PI_2F - a) : a;
    a = (x < 0.f) ? (PI_F - a) : a;
    return copysignf(a, y);
}

static __device__ __forceinline__ float pdiff(float a, float b, float c, float d) {
    // est=a+ib, ref=c+id: angle(ref*conj(est)) = atan2(d*a - c*b, c*a + d*b)
    return fast_atan2(fmaf(d, a, -(c * b)), fmaf(c, a, d * b));
}

static __device__ __forceinline__ float wrap_abs(float x) {
    const float PI_F     = 3.14159274101257324f;
    const float TWO_PI_F = 6.28318548202514648f;
    float u = fabsf(x);
    return u > PI_F ? TWO_PI_F - u : u;
}

struct Row8 { float4 a0, a1, b0, b1, c0, c1, e0, e1; };

static __device__ __forceinline__ void calc8(const Row8& r, float d[8]) {
    d[0] = pdiff(r.a0.x, r.b0.x, r.c0.x, r.e0.x);
    d[1] = pdiff(r.a0.y, r.b0.y, r.c0.y, r.e0.y);
    d[2] = pdiff(r.a0.z, r.b0.z, r.c0.z, r.e0.z);
    d[3] = pdiff(r.a0.w, r.b0.w, r.c0.w, r.e0.w);
    d[4] = pdiff(r.a1.x, r.b1.x, r.c1.x, r.e1.x);
    d[5] = pdiff(r.a1.y, r.b1.y, r.c1.y, r.e1.y);
    d[6] = pdiff(r.a1.z, r.b1.z, r.c1.z, r.e1.z);
    d[7] = pdiff(r.a1.w, r.b1.w, r.c1.w, r.e1.w);
}

// accumulate one row's three loss terms; updates dp[] (f-1 carry)
static __device__ __forceinline__ float acc_row(const float d[8], float dp[8], int lane) {
    float dt = __shfl_up(d[7], 1, 64);
    if (lane == 0) dt = 0.f;                  // t==0 neighbor
    float s = 0.f;
    #pragma unroll
    for (int k = 0; k < 8; ++k) {
        s += fabsf(d[k]);                     // ip
        s += wrap_abs(dp[k] - d[k]);          // gd
        s += wrap_abs(dt - d[k]);             // ptd
        dt = d[k];
        dp[k] = d[k];
    }
    return s;
}

__global__ __launch_bounds__(256, 2) void phase_loss_k(
    const float* __restrict__ er, const float* __restrict__ ei,
    const float* __restrict__ rr, const float* __restrict__ ri,
    float* __restrict__ slots)
{
    const int tid  = threadIdx.x;
    const int lane = tid & 63;
    const int wid  = (blockIdx.x << 2) | (tid >> 6);   // 0..2063
    // stream A = 2*wid, stream B = 2*wid+1
    const int sa = wid * 2, sb = sa + 1;
    const int ba = sa / CHUNKS,            bb = sb / CHUNKS;
    const int f0a = (sa - ba * CHUNKS) * RPW, f0b = (sb - bb * CHUNKS) * RPW;
    const int basea = ba * (NF * NT),      baseb = bb * (NF * NT);
    const int nva = (NF - f0a < RPW) ? (NF - f0a) : RPW;
    const int nvb = (NF - f0b < RPW) ? (NF - f0b) : RPW;

#define LOAD_ROW(dst, base_, f_) do {                            \
        const int _i = (base_) + (f_) * NT + lane * 8;           \
        dst.a0 = *(const float4*)(er + _i);                      \
        dst.a1 = *(const float4*)(er + _i + 4);                  \
        dst.b0 = *(const float4*)(ei + _i);                      \
        dst.b1 = *(const float4*)(ei + _i + 4);                  \
        dst.c0 = *(const float4*)(rr + _i);                      \
        dst.c1 = *(const float4*)(rr + _i + 4);                  \
        dst.e0 = *(const float4*)(ri + _i);                      \
        dst.e1 = *(const float4*)(ri + _i + 4);                  \
    } while (0)

    float s = 0.f;
    float dpa[8], dpb[8], da[8], db[8];
    Row8 Ra, Rb;

    // ---- halo phase (both streams' halo loads in flight together) ----
    if (f0a > 0) LOAD_ROW(Ra, basea, f0a - 1);
    if (f0b > 0) LOAD_ROW(Rb, baseb, f0b - 1);
    if (f0a > 0) {
        calc8(Ra, dpa);                       // Rb halo still outstanding
    } else {
        #pragma unroll
        for (int k = 0; k < 8; ++k) dpa[k] = 0.f;
    }
    LOAD_ROW(Ra, basea, f0a);                 // A row 0 in flight during B halo calc
    if (f0b > 0) {
        calc8(Rb, dpb);
    } else {
        #pragma unroll
        for (int k = 0; k < 8; ++k) dpb[k] = 0.f;
    }
    LOAD_ROW(Rb, baseb, f0b);                 // B row 0 in flight

    // ---- main interleave: calc(X) overlaps the other stream's loads ----
    // r = 0
    calc8(Ra, da);  s += acc_row(da, dpa, lane);
    if (nva > 1) LOAD_ROW(Ra, basea, f0a + 1);
    calc8(Rb, db);  s += acc_row(db, dpb, lane);
    if (nvb > 1) LOAD_ROW(Rb, baseb, f0b + 1);
    // r = 1
    if (nva > 1) { calc8(Ra, da);  s += acc_row(da, dpa, lane); }
    if (nva > 2) LOAD_ROW(Ra, basea, f0a + 2);
    if (nvb > 1) { calc8(Rb, db);  s += acc_row(db, dpb, lane); }
    if (nvb > 2) LOAD_ROW(Rb, baseb, f0b + 2);
    // r = 2
    if (nva > 2) { calc8(Ra, da);  s += acc_row(da, dpa, lane); }
    if (nva > 3) LOAD_ROW(Ra, basea, f0a + 3);
    if (nvb > 2) { calc8(Rb, db);  s += acc_row(db, dpb, lane); }
    if (nvb > 3) LOAD_ROW(Rb, baseb, f0b + 3);
    // r = 3
    if (nva > 3) { calc8(Ra, da);  s += acc_row(da, dpa, lane); }
    if (nvb > 3) { calc8(Rb, db);  s += acc_row(db, dpb, lane); }
#undef LOAD_ROW

    // per-wave reduce, tiny cross-wave combine, one plain store per block
    #pragma unroll
    for (int off = 32; off > 0; off >>= 1)
        s += __shfl_down(s, off, 64);
    __shared__ float ws4[4];
    if (lane == 0) ws4[tid >> 6] = s;
    __syncthreads();
    if (tid == 0) slots[blockIdx.x] = ws4[0] + ws4[1] + ws4[2] + ws4[3];
}

__global__ __launch_bounds__(256) void finalize_k(const float* __restrict__ slots,
                                                  float* __restrict__ out)
{
    int tid = threadIdx.x;
    float s = 0.f;
    for (int i = tid; i < NBLOCKS; i += 256) s += slots[i];
    #pragma unroll
    for (int off = 32; off > 0; off >>= 1)
        s += __shfl_down(s, off, 64);
    __shared__ float wsum[4];
    if ((tid & 63) == 0) wsum[tid >> 6] = s;
    __syncthreads();
    if (tid == 0) {
        double tot = (double)wsum[0] + (double)wsum[1] + (double)wsum[2] + (double)wsum[3];
        out[0] = (float)(tot / (double)NTOT);
    }
}

extern "C" void kernel_launch(void* const* d_in, const int* in_sizes, int n_in,
                              void* d_out, int out_size, void* d_ws, size_t ws_size,
                              hipStream_t stream) {
    const float* er = (const float*)d_in[0];
    const float* ei = (const float*)d_in[1];
    const float* rr = (const float*)d_in[2];
    const float* ri = (const float*)d_in[3];
    float* out   = (float*)d_out;
    float* slots = (float*)d_ws;              // NBLOCKS fp32, fully rewritten each call

    phase_loss_k<<<NBLOCKS, 256, 0, stream>>>(er, ei, rr, ri, slots);
    finalize_k<<<1, 256, 0, stream>>>(slots, out);
}